// Round 7
// baseline (245.162 us; speedup 1.0000x reference)
//
#include <hip/hip_runtime.h>
#include <stdint.h>

#define NS 10
#define DIM 512
#define NQ 4096
#define NP 1024

typedef unsigned short ushort_t;
typedef __bf16 bf16el_t;
typedef bf16el_t bf16x8 __attribute__((ext_vector_type(8)));
typedef float floatx4 __attribute__((ext_vector_type(4)));

// ================= threefry2x32-20 (JAX-compatible, partitionable path) =================
__host__ __device__ __forceinline__ uint32_t rotl32(uint32_t x, int r) {
  return (x << r) | (x >> (32 - r));
}

__host__ __device__ __forceinline__ void threefry2x32(uint32_t k0, uint32_t k1,
                                                      uint32_t x0, uint32_t x1,
                                                      uint32_t* o0, uint32_t* o1) {
  uint32_t ks2 = k0 ^ k1 ^ 0x1BD11BDAu;
  x0 += k0; x1 += k1;
#define TF_R(r) { x0 += x1; x1 = rotl32(x1, r); x1 ^= x0; }
  TF_R(13) TF_R(15) TF_R(26) TF_R(6)   x0 += k1;  x1 += ks2 + 1u;
  TF_R(17) TF_R(29) TF_R(16) TF_R(24)  x0 += ks2; x1 += k0 + 2u;
  TF_R(13) TF_R(15) TF_R(26) TF_R(6)   x0 += k0;  x1 += k1 + 3u;
  TF_R(17) TF_R(29) TF_R(16) TF_R(24)  x0 += k1;  x1 += ks2 + 4u;
  TF_R(13) TF_R(15) TF_R(26) TF_R(6)   x0 += ks2; x1 += k0 + 5u;
#undef TF_R
  *o0 = x0; *o1 = x1;
}

__device__ __forceinline__ uint32_t jax_random_bits(uint32_t k0, uint32_t k1, uint32_t idx) {
  uint32_t o0, o1;
  threefry2x32(k0, k1, 0u, idx, &o0, &o1);
  return o0 ^ o1;
}

// XLA ErfInv32 (Giles polynomial)
__device__ __forceinline__ float erfinvf_xla(float x) {
  float w = -log1pf(-x * x);
  float p;
  if (w < 5.0f) {
    w -= 2.5f;
    p = 2.81022636e-08f;
    p = fmaf(p, w, 3.43273939e-07f);
    p = fmaf(p, w, -3.5233877e-06f);
    p = fmaf(p, w, -4.39150654e-06f);
    p = fmaf(p, w, 0.00021858087f);
    p = fmaf(p, w, -0.00125372503f);
    p = fmaf(p, w, -0.00417768164f);
    p = fmaf(p, w, 0.246640727f);
    p = fmaf(p, w, 1.50140941f);
  } else {
    w = sqrtf(w) - 3.0f;
    p = -0.000200214257f;
    p = fmaf(p, w, 0.000100950558f);
    p = fmaf(p, w, 0.00134934322f);
    p = fmaf(p, w, -0.00367342844f);
    p = fmaf(p, w, 0.00573950773f);
    p = fmaf(p, w, -0.0076224613f);
    p = fmaf(p, w, 0.00943887047f);
    p = fmaf(p, w, 1.00167406f);
    p = fmaf(p, w, 2.83297682f);
  }
  return p * x;
}

__device__ __forceinline__ float jax_bits_to_normal(uint32_t bits) {
  float f = __uint_as_float((bits >> 9) | 0x3F800000u) - 1.0f;
  float u = f * 2.0f - 0.99999994f;
  u = fmaxf(u, -0.99999994f);
  return 1.41421356f * erfinvf_xla(u);
}

__device__ __forceinline__ float softplusf(float x) { return log1pf(expf(x)); }

__device__ __forceinline__ float bf2f(ushort_t u) {
  return __uint_as_float(((uint32_t)u) << 16);
}
__device__ __forceinline__ ushort_t f2bf(float f) {
  uint32_t u = __float_as_uint(f);
  u += 0x7FFFu + ((u >> 16) & 1u);
  return (ushort_t)(u >> 16);
}

// async global->LDS, 16B per lane. LDS dst = wave-uniform base + lane*16.
__device__ __forceinline__ void gll16(const void* g, void* l) {
  __builtin_amdgcn_global_load_lds(
      (const __attribute__((address_space(1))) uint32_t*)g,
      (__attribute__((address_space(3))) uint32_t*)l, 16, 0, 0);
}

// ================= fused prep: gen_w | cvt_q | cvt_p+sqp | gen_b | zero sqq ==============
__global__ __launch_bounds__(256) void prep_kernel(const float* __restrict__ qf,
                                                   const float* __restrict__ pf,
                                                   const float* __restrict__ wmu,
                                                   const float* __restrict__ wrho,
                                                   const float* __restrict__ bmu,
                                                   const float* __restrict__ brho,
                                                   ushort_t* __restrict__ wt,
                                                   ushort_t* __restrict__ qb,
                                                   ushort_t* __restrict__ pb,
                                                   float* __restrict__ sqp,
                                                   float* __restrict__ bvec,
                                                   float* __restrict__ sqq,
                                                   uint32_t kw0, uint32_t kw1,
                                                   uint32_t kb0, uint32_t kb1) {
  const int blk = blockIdx.x;
  const int tid = threadIdx.x;
  if (blk < 10240) {                     // ---- gen_w: wt[s][e][k], 2,621,440 elems ----
    uint32_t t = blk * 256u + tid;
    uint32_t s = t >> 18;
    uint32_t r = t & 0x3FFFFu;
    uint32_t e = r >> 9;
    uint32_t k = r & 511u;
    uint32_t eps_idx = (s << 18) | (k << 9) | e;    // JAX order [s][k][e]
    uint32_t bits = jax_random_bits(kw0, kw1, eps_idx);
    float n = jax_bits_to_normal(bits);
    uint32_t mi = (k << 9) | e;
    float w = wmu[mi] + softplusf(wrho[mi]) * n;
    wt[t] = f2bf(w);
  } else if (blk < 12288) {              // ---- cvt_q: 2,097,152 floats ----
    int i = ((blk - 10240) * 256 + tid) * 4;
    float4 v = *(const float4*)&qf[i];
    uint2 r;
    r.x = (uint32_t)f2bf(v.x) | ((uint32_t)f2bf(v.y) << 16);
    r.y = (uint32_t)f2bf(v.z) | ((uint32_t)f2bf(v.w) << 16);
    *(uint2*)&qb[i] = r;
  } else if (blk < 12544) {              // ---- cvt_p + sqp: 4 protos / block ----
    int p = (blk - 12288) * 4 + (tid >> 6);
    int lane = tid & 63;
    const float* src = pf + p * DIM + lane * 8;
    float4 a = *(const float4*)src;
    float4 b = *(const float4*)(src + 4);
    float vals[8] = {a.x, a.y, a.z, a.w, b.x, b.y, b.z, b.w};
    ushort_t o[8];
    float ss = 0.f;
#pragma unroll
    for (int i = 0; i < 8; ++i) {
      o[i] = f2bf(vals[i]);
      float f = bf2f(o[i]);
      ss += f * f;
    }
    *(uint4*)&pb[p * DIM + lane * 8] = *(const uint4*)o;
#pragma unroll
    for (int off = 32; off; off >>= 1) ss += __shfl_xor(ss, off, 64);
    if (lane == 0) sqp[p] = ss;
  } else if (blk < 12564) {              // ---- gen_b: 5120 ----
    uint32_t t2 = (blk - 12544) * 256u + tid;
    uint32_t e = t2 & 511u;
    uint32_t bits = jax_random_bits(kb0, kb1, t2);
    float n = jax_bits_to_normal(bits);
    bvec[t2] = bmu[e] + softplusf(brho[e]) * n;
  } else {                               // ---- zero sqq: 40960 floats ----
    int i = (blk - 12564) * 256 + tid;
    sqq[i] = 0.f;
  }
}

// ================= GEMM1: tq[s] = q @ W_s + b_s (R4-proven) =================
// 128x128 tile, BK=64, global_load_lds + 8-chunk swizzle, 4 waves of 64x64. grid (32,4,10).
// Epilogue: LDS transpose -> coalesced dwordx4 bf16 stores + fused sqq atomics.
__global__ __launch_bounds__(256) void gemm_tq_kernel(const ushort_t* __restrict__ qb,
                                                      const ushort_t* __restrict__ wt,
                                                      const float* __restrict__ bvec,
                                                      ushort_t* __restrict__ tq,
                                                      float* __restrict__ sqq) {
  __shared__ __align__(16) ushort_t ls[2 * 128 * 64];   // 32 KB: lsA | lsB, reused by epilogue
  ushort_t* lsA = ls;
  ushort_t* lsB = ls + 128 * 64;
  const int lane = threadIdx.x & 63;
  const int wave = threadIdx.x >> 6;
  const int wm = wave >> 1, wn = wave & 1;   // 2x2 wave grid, 64x64 each
  const int qBase = blockIdx.x * 128;
  const int eBase = blockIdx.y * 128;
  const int s = blockIdx.z;
  const ushort_t* wbase = wt + (size_t)s * (DIM * DIM);  // [e][k]
  const int srow = lane >> 3;                       // 0..7
  const int scol = ((lane & 7) ^ srow) * 16;        // swizzled global chunk (bytes)
  const char* gA = (const char*)qb + (size_t)(qBase + wave * 32 + srow) * (DIM * 2) + scol;
  const char* gB = (const char*)wbase + (size_t)(eBase + wave * 32 + srow) * (DIM * 2) + scol;
  char* lA = (char*)&lsA[wave * 32 * 64];
  char* lB = (char*)&lsB[wave * 32 * 64];
  const int cn = lane & 15;
  const int cn7 = cn & 7;
  const int jc = lane >> 4;                         // 0..3
  const floatx4 fzero = {0.f, 0.f, 0.f, 0.f};
  floatx4 acc[4][4];
#pragma unroll
  for (int mi = 0; mi < 4; ++mi)
#pragma unroll
    for (int ni = 0; ni < 4; ++ni) acc[mi][ni] = fzero;

  for (int kt = 0; kt < 8; ++kt) {
    __syncthreads();
#pragma unroll
    for (int j = 0; j < 4; ++j) {
      gll16(gA + (size_t)j * 8 * (DIM * 2), lA + j * 1024);
      gll16(gB + (size_t)j * 8 * (DIM * 2), lB + j * 1024);
    }
    gA += 128; gB += 128;
    __syncthreads();
#pragma unroll
    for (int c = 0; c < 8; c += 4) {                // logical chunk base (kk = c*8)
      const int po = ((c + jc) ^ cn7) << 3;         // swizzled element offset in row
      bf16x8 aF[4], bF[4];
#pragma unroll
      for (int mi = 0; mi < 4; ++mi)
        aF[mi] = *(const bf16x8*)&lsA[(wm * 64 + mi * 16 + cn) * 64 + po];
#pragma unroll
      for (int ni = 0; ni < 4; ++ni)
        bF[ni] = *(const bf16x8*)&lsB[(wn * 64 + ni * 16 + cn) * 64 + po];
#pragma unroll
      for (int mi = 0; mi < 4; ++mi)
#pragma unroll
        for (int ni = 0; ni < 4; ++ni)
          acc[mi][ni] = __builtin_amdgcn_mfma_f32_16x16x32_bf16(aF[mi], bF[ni], acc[mi][ni], 0, 0, 0);
    }
  }

  // ---- epilogue: per-wave 64x64 transpose through LDS (swizzled), coalesced stores ----
  __syncthreads();                                  // everyone done reading lsA/lsB
  ushort_t* area = ls + wave * 4096;                // 8 KB/wave: 64 rows x 64 cols
  float bv[4];
#pragma unroll
  for (int ni = 0; ni < 4; ++ni) bv[ni] = bvec[s * DIM + eBase + wn * 64 + ni * 16 + cn];
  const int jc4 = jc * 4;
#pragma unroll
  for (int mi = 0; mi < 4; ++mi)
#pragma unroll
    for (int ni = 0; ni < 4; ++ni)
#pragma unroll
      for (int r = 0; r < 4; ++r) {
        const int lr = mi * 16 + jc4 + r;           // local q row
        const int lc = ni * 16 + cn;                // local e col
        const int off = lr * 64 + (((lc >> 3) ^ (lr & 7)) << 3) + (lc & 7);
        area[off] = f2bf(acc[mi][ni][r] + bv[ni]);
      }
  __syncthreads();
  const int rr = lane >> 3;                         // 0..7: row within pass
  const int ch = lane & 7;                          // e-chunk
  const int physc = ch ^ rr;
  const size_t tqs = (size_t)s * (NQ * DIM);
#pragma unroll
  for (int pass = 0; pass < 8; ++pass) {
    const int lr = pass * 8 + rr;
    uint4 v = *(const uint4*)&area[lr * 64 + physc * 8];
    uint32_t wsv[4] = {v.x, v.y, v.z, v.w};
    float ss = 0.f;
#pragma unroll
    for (int i = 0; i < 4; ++i) {
      float lo = bf2f((ushort_t)(wsv[i] & 0xFFFFu));
      float hi = bf2f((ushort_t)(wsv[i] >> 16));
      ss += lo * lo + hi * hi;
    }
    ss += __shfl_xor(ss, 1, 64);
    ss += __shfl_xor(ss, 2, 64);
    ss += __shfl_xor(ss, 4, 64);
    const int q = qBase + wm * 64 + lr;
    *(uint4*)&tq[tqs + (size_t)q * DIM + eBase + wn * 64 + ch * 8] = v;
    if (ch == 0) atomicAdd(&sqq[s * NQ + q], ss);
  }
}

// ================= GEMM2 fused dist/mean/std — R4 structure, s processed in PAIRS =========
// 64q x 128p tile, BK=128, global_load_lds + 16-chunk swizzle, 4 waves of 32x64.
// Two samples share each staged B tile: B-fragment LDS reads halve, barriers halve.
// grid (64,8) (q fastest — proven L3-friendly; sharers staggered across dispatch).
__global__ __launch_bounds__(256) void gemm_dist_kernel(const ushort_t* __restrict__ tq,
                                                        const ushort_t* __restrict__ pb,
                                                        const float* __restrict__ sqq,
                                                        const float* __restrict__ sqp,
                                                        float* __restrict__ out) {
  __shared__ __align__(16) ushort_t lsA[2 * 64 * 128];   // 32 KB: A(s), A(s+1)
  __shared__ __align__(16) ushort_t lsB[128 * 128];      // 32 KB
  const int lane = threadIdx.x & 63;
  const int wave = threadIdx.x >> 6;
  const int wm = wave >> 1;            // q offset 32*wm
  const int wn = wave & 1;             // p offset 64*wn
  const int qBase = blockIdx.x * 64;
  const int pBase = blockIdx.y * 128;
  const int srow = lane >> 4;          // 0..3 (4 rows per gll call)
  const int scc = lane & 15;           // phys chunk 0..15
  const int sccx = scc ^ srow;         // base swizzled col (g=0)
  const char* gAb = (const char*)tq + (size_t)(qBase + wave * 16 + srow) * (DIM * 2);
  const char* gBb = (const char*)pb + (size_t)(pBase + wave * 32 + srow) * (DIM * 2);
  char* lA = (char*)lsA + wave * 4096;  // 16 rows * 256 B within each 16 KB buffer
  char* lB = (char*)lsB + wave * 8192;  // 32 rows * 256 B
  const int cn = lane & 15;
  const int jc = lane >> 4;
  const int rq = jc * 4;
  const floatx4 fzero = {0.f, 0.f, 0.f, 0.f};

  float sum[2][4][4] = {};   // [mi][ni][r], accumulated over all samples
  float ssq[2][4][4] = {};
  float sqp_v[4];
#pragma unroll
  for (int ni = 0; ni < 4; ++ni) sqp_v[ni] = sqp[pBase + wn * 64 + ni * 16 + cn];

  for (int s0 = 0; s0 < NS; s0 += 2) {
    floatx4 acc[2][2][4];    // [sp][mi][ni]
#pragma unroll
    for (int sp = 0; sp < 2; ++sp)
#pragma unroll
      for (int mi = 0; mi < 2; ++mi)
#pragma unroll
        for (int ni = 0; ni < 4; ++ni) acc[sp][mi][ni] = fzero;

    const char* gA0 = gAb + (size_t)s0 * (NQ * DIM * 2);
    const char* gA1 = gA0 + (size_t)(NQ * DIM * 2);
    const char* gBk = gBb;
    for (int kt = 0; kt < 4; ++kt) {   // K chunks of 128
      __syncthreads();
#pragma unroll
      for (int g = 0; g < 4; ++g) {
        const size_t off = (size_t)g * 4 * (DIM * 2) + (size_t)((sccx ^ (g * 4)) << 4);
        gll16(gA0 + off, lA + g * 1024);
        gll16(gA1 + off, lA + 16384 + g * 1024);
      }
#pragma unroll
      for (int g = 0; g < 8; ++g)
        gll16(gBk + (size_t)g * 4 * (DIM * 2) + (size_t)((sccx ^ ((g & 3) * 4)) << 4),
              lB + g * 1024);
      gA0 += 256; gA1 += 256; gBk += 256;
      __syncthreads();
#pragma unroll
      for (int c4 = 0; c4 < 4; ++c4) {
        const int po = (((c4 * 4 + jc) ^ cn) & 15) << 3;   // swizzled element offset
        bf16x8 bF[4];
#pragma unroll
        for (int ni = 0; ni < 4; ++ni)
          bF[ni] = *(const bf16x8*)&lsB[(wn * 64 + ni * 16 + cn) * 128 + po];
#pragma unroll
        for (int sp = 0; sp < 2; ++sp) {
          bf16x8 aF[2];
#pragma unroll
          for (int mi = 0; mi < 2; ++mi)
            aF[mi] = *(const bf16x8*)&lsA[sp * 8192 + (wm * 32 + mi * 16 + cn) * 128 + po];
#pragma unroll
          for (int mi = 0; mi < 2; ++mi)
#pragma unroll
            for (int ni = 0; ni < 4; ++ni)
              acc[sp][mi][ni] =
                  __builtin_amdgcn_mfma_f32_16x16x32_bf16(aF[mi], bF[ni], acc[sp][mi][ni], 0, 0, 0);
        }
      }
    }
    // fold both samples into running stats (ssq accumulates pre-sqrt sqd)
#pragma unroll
    for (int sp = 0; sp < 2; ++sp) {
      const int s = s0 + sp;
#pragma unroll
      for (int mi = 0; mi < 2; ++mi) {
        float4 aqv = *(const float4*)&sqq[s * NQ + qBase + wm * 32 + mi * 16 + rq];
        float aqa[4] = {aqv.x, aqv.y, aqv.z, aqv.w};
#pragma unroll
        for (int r = 0; r < 4; ++r) {
          float aq = aqa[r];
#pragma unroll
          for (int ni = 0; ni < 4; ++ni) {
            float sqd = fmaxf(fmaf(-2.0f, acc[sp][mi][ni][r], aq + sqp_v[ni]), 1e-12f);
            sum[mi][ni][r] += sqrtf(sqd);
            ssq[mi][ni][r] += sqd;
          }
        }
      }
    }
  }
#pragma unroll
  for (int mi = 0; mi < 2; ++mi)
#pragma unroll
    for (int ni = 0; ni < 4; ++ni)
#pragma unroll
      for (int r = 0; r < 4; ++r) {
        int q = qBase + wm * 32 + mi * 16 + rq + r;
        int p = pBase + wn * 64 + ni * 16 + cn;
        float sm = sum[mi][ni][r];
        float mean = sm * 0.1f;
        float var = (ssq[mi][ni][r] - sm * sm * 0.1f) * (1.0f / 9.0f);
        out[(size_t)q * NP + p] = mean;
        out[(size_t)NQ * NP + (size_t)q * NP + p] = sqrtf(fmaxf(var, 0.0f));
      }
}

// ================= launch =================
extern "C" void kernel_launch(void* const* d_in, const int* in_sizes, int n_in,
                              void* d_out, int out_size, void* d_ws, size_t ws_size,
                              hipStream_t stream) {
  const float* qf   = (const float*)d_in[0];
  const float* pf   = (const float*)d_in[1];
  const float* wmu  = (const float*)d_in[2];
  const float* wrho = (const float*)d_in[3];
  const float* bmu  = (const float*)d_in[4];
  const float* brho = (const float*)d_in[5];
  float* out = (float*)d_out;
  char* ws = (char*)d_ws;
  ushort_t* wt   = (ushort_t*)(ws);              //  5,242,880  W^T bf16 [s][e][k]
  ushort_t* qb   = (ushort_t*)(ws + 5242880);    //  4,194,304  query bf16
  ushort_t* pb   = (ushort_t*)(ws + 9437184);    //  1,048,576  proto bf16
  float*    bvec = (float*)   (ws + 10485760);   //     20,480  bias samples
  float*    sqp  = (float*)   (ws + 10506240);   //      4,096  ||p||^2
  ushort_t* tq   = (ushort_t*)(ws + 10510336);   // 41,943,040  tq bf16 [s][q][e]
  float*    sqq  = (float*)   (ws + 52453376);   //    163,840  ||tq||^2 (atomic-accumulated)

  uint32_t kw0, kw1, kb0, kb1;
  threefry2x32(0u, 42u, 0u, 0u, &kw0, &kw1);
  threefry2x32(0u, 42u, 0u, 1u, &kb0, &kb1);

  hipLaunchKernelGGL(prep_kernel, dim3(12724), dim3(256), 0, stream,
                     qf, pf, wmu, wrho, bmu, brho, wt, qb, pb, sqp, bvec, sqq,
                     kw0, kw1, kb0, kb1);
  hipLaunchKernelGGL(gemm_tq_kernel, dim3(32, 4, 10), dim3(256), 0, stream, qb, wt, bvec, tq, sqq);
  hipLaunchKernelGGL(gemm_dist_kernel, dim3(64, 8), dim3(256), 0, stream, tq, pb, sqq, sqp, out);
}

// Round 8
// 201.996 us; speedup vs baseline: 1.2137x; 1.2137x over previous
//
#include <hip/hip_runtime.h>
#include <stdint.h>

#define NS 10
#define DIM 512
#define NQ 4096
#define NP 1024

typedef unsigned short ushort_t;
typedef __bf16 bf16el_t;
typedef bf16el_t bf16x8 __attribute__((ext_vector_type(8)));
typedef float floatx4 __attribute__((ext_vector_type(4)));

// ================= threefry2x32-20 (JAX-compatible, partitionable path) =================
__host__ __device__ __forceinline__ uint32_t rotl32(uint32_t x, int r) {
  return (x << r) | (x >> (32 - r));
}

__host__ __device__ __forceinline__ void threefry2x32(uint32_t k0, uint32_t k1,
                                                      uint32_t x0, uint32_t x1,
                                                      uint32_t* o0, uint32_t* o1) {
  uint32_t ks2 = k0 ^ k1 ^ 0x1BD11BDAu;
  x0 += k0; x1 += k1;
#define TF_R(r) { x0 += x1; x1 = rotl32(x1, r); x1 ^= x0; }
  TF_R(13) TF_R(15) TF_R(26) TF_R(6)   x0 += k1;  x1 += ks2 + 1u;
  TF_R(17) TF_R(29) TF_R(16) TF_R(24)  x0 += ks2; x1 += k0 + 2u;
  TF_R(13) TF_R(15) TF_R(26) TF_R(6)   x0 += k0;  x1 += k1 + 3u;
  TF_R(17) TF_R(29) TF_R(16) TF_R(24)  x0 += k1;  x1 += ks2 + 4u;
  TF_R(13) TF_R(15) TF_R(26) TF_R(6)   x0 += ks2; x1 += k0 + 5u;
#undef TF_R
  *o0 = x0; *o1 = x1;
}

__device__ __forceinline__ uint32_t jax_random_bits(uint32_t k0, uint32_t k1, uint32_t idx) {
  uint32_t o0, o1;
  threefry2x32(k0, k1, 0u, idx, &o0, &o1);
  return o0 ^ o1;
}

// XLA ErfInv32 (Giles polynomial)
__device__ __forceinline__ float erfinvf_xla(float x) {
  float w = -log1pf(-x * x);
  float p;
  if (w < 5.0f) {
    w -= 2.5f;
    p = 2.81022636e-08f;
    p = fmaf(p, w, 3.43273939e-07f);
    p = fmaf(p, w, -3.5233877e-06f);
    p = fmaf(p, w, -4.39150654e-06f);
    p = fmaf(p, w, 0.00021858087f);
    p = fmaf(p, w, -0.00125372503f);
    p = fmaf(p, w, -0.00417768164f);
    p = fmaf(p, w, 0.246640727f);
    p = fmaf(p, w, 1.50140941f);
  } else {
    w = sqrtf(w) - 3.0f;
    p = -0.000200214257f;
    p = fmaf(p, w, 0.000100950558f);
    p = fmaf(p, w, 0.00134934322f);
    p = fmaf(p, w, -0.00367342844f);
    p = fmaf(p, w, 0.00573950773f);
    p = fmaf(p, w, -0.0076224613f);
    p = fmaf(p, w, 0.00943887047f);
    p = fmaf(p, w, 1.00167406f);
    p = fmaf(p, w, 2.83297682f);
  }
  return p * x;
}

__device__ __forceinline__ float jax_bits_to_normal(uint32_t bits) {
  float f = __uint_as_float((bits >> 9) | 0x3F800000u) - 1.0f;
  float u = f * 2.0f - 0.99999994f;
  u = fmaxf(u, -0.99999994f);
  return 1.41421356f * erfinvf_xla(u);
}

__device__ __forceinline__ float softplusf(float x) { return log1pf(expf(x)); }

__device__ __forceinline__ float bf2f(ushort_t u) {
  return __uint_as_float(((uint32_t)u) << 16);
}
__device__ __forceinline__ ushort_t f2bf(float f) {
  uint32_t u = __float_as_uint(f);
  u += 0x7FFFu + ((u >> 16) & 1u);
  return (ushort_t)(u >> 16);
}

// async global->LDS, 16B per lane. LDS dst = wave-uniform base + lane*16.
__device__ __forceinline__ void gll16(const void* g, void* l) {
  __builtin_amdgcn_global_load_lds(
      (const __attribute__((address_space(1))) uint32_t*)g,
      (__attribute__((address_space(3))) uint32_t*)l, 16, 0, 0);
}

// ================= fused prep: gen_w | cvt_q | cvt_p+sqp | gen_b | zero sqq ==============
__global__ __launch_bounds__(256) void prep_kernel(const float* __restrict__ qf,
                                                   const float* __restrict__ pf,
                                                   const float* __restrict__ wmu,
                                                   const float* __restrict__ wrho,
                                                   const float* __restrict__ bmu,
                                                   const float* __restrict__ brho,
                                                   ushort_t* __restrict__ wt,
                                                   ushort_t* __restrict__ qb,
                                                   ushort_t* __restrict__ pb,
                                                   float* __restrict__ sqp,
                                                   float* __restrict__ bvec,
                                                   float* __restrict__ sqq,
                                                   uint32_t kw0, uint32_t kw1,
                                                   uint32_t kb0, uint32_t kb1) {
  const int blk = blockIdx.x;
  const int tid = threadIdx.x;
  if (blk < 10240) {                     // ---- gen_w: wt[s][e][k], 2,621,440 elems ----
    uint32_t t = blk * 256u + tid;
    uint32_t s = t >> 18;
    uint32_t r = t & 0x3FFFFu;
    uint32_t e = r >> 9;
    uint32_t k = r & 511u;
    uint32_t eps_idx = (s << 18) | (k << 9) | e;    // JAX order [s][k][e]
    uint32_t bits = jax_random_bits(kw0, kw1, eps_idx);
    float n = jax_bits_to_normal(bits);
    uint32_t mi = (k << 9) | e;
    float w = wmu[mi] + softplusf(wrho[mi]) * n;
    wt[t] = f2bf(w);
  } else if (blk < 12288) {              // ---- cvt_q: 2,097,152 floats ----
    int i = ((blk - 10240) * 256 + tid) * 4;
    float4 v = *(const float4*)&qf[i];
    uint2 r;
    r.x = (uint32_t)f2bf(v.x) | ((uint32_t)f2bf(v.y) << 16);
    r.y = (uint32_t)f2bf(v.z) | ((uint32_t)f2bf(v.w) << 16);
    *(uint2*)&qb[i] = r;
  } else if (blk < 12544) {              // ---- cvt_p + sqp: 4 protos / block ----
    int p = (blk - 12288) * 4 + (tid >> 6);
    int lane = tid & 63;
    const float* src = pf + p * DIM + lane * 8;
    float4 a = *(const float4*)src;
    float4 b = *(const float4*)(src + 4);
    float vals[8] = {a.x, a.y, a.z, a.w, b.x, b.y, b.z, b.w};
    ushort_t o[8];
    float ss = 0.f;
#pragma unroll
    for (int i = 0; i < 8; ++i) {
      o[i] = f2bf(vals[i]);
      float f = bf2f(o[i]);
      ss += f * f;
    }
    *(uint4*)&pb[p * DIM + lane * 8] = *(const uint4*)o;
#pragma unroll
    for (int off = 32; off; off >>= 1) ss += __shfl_xor(ss, off, 64);
    if (lane == 0) sqp[p] = ss;
  } else if (blk < 12564) {              // ---- gen_b: 5120 ----
    uint32_t t2 = (blk - 12544) * 256u + tid;
    uint32_t e = t2 & 511u;
    uint32_t bits = jax_random_bits(kb0, kb1, t2);
    float n = jax_bits_to_normal(bits);
    bvec[t2] = bmu[e] + softplusf(brho[e]) * n;
  } else {                               // ---- zero sqq: 40960 floats ----
    int i = (blk - 12564) * 256 + tid;
    sqq[i] = 0.f;
  }
}

// ================= GEMM1: tq[s] = q @ W_s + b_s (R4-proven, unchanged) =================
__global__ __launch_bounds__(256) void gemm_tq_kernel(const ushort_t* __restrict__ qb,
                                                      const ushort_t* __restrict__ wt,
                                                      const float* __restrict__ bvec,
                                                      ushort_t* __restrict__ tq,
                                                      float* __restrict__ sqq) {
  __shared__ __align__(16) ushort_t ls[2 * 128 * 64];   // 32 KB: lsA | lsB, reused by epilogue
  ushort_t* lsA = ls;
  ushort_t* lsB = ls + 128 * 64;
  const int lane = threadIdx.x & 63;
  const int wave = threadIdx.x >> 6;
  const int wm = wave >> 1, wn = wave & 1;   // 2x2 wave grid, 64x64 each
  const int qBase = blockIdx.x * 128;
  const int eBase = blockIdx.y * 128;
  const int s = blockIdx.z;
  const ushort_t* wbase = wt + (size_t)s * (DIM * DIM);  // [e][k]
  const int srow = lane >> 3;                       // 0..7
  const int scol = ((lane & 7) ^ srow) * 16;        // swizzled global chunk (bytes)
  const char* gA = (const char*)qb + (size_t)(qBase + wave * 32 + srow) * (DIM * 2) + scol;
  const char* gB = (const char*)wbase + (size_t)(eBase + wave * 32 + srow) * (DIM * 2) + scol;
  char* lA = (char*)&lsA[wave * 32 * 64];
  char* lB = (char*)&lsB[wave * 32 * 64];
  const int cn = lane & 15;
  const int cn7 = cn & 7;
  const int jc = lane >> 4;                         // 0..3
  const floatx4 fzero = {0.f, 0.f, 0.f, 0.f};
  floatx4 acc[4][4];
#pragma unroll
  for (int mi = 0; mi < 4; ++mi)
#pragma unroll
    for (int ni = 0; ni < 4; ++ni) acc[mi][ni] = fzero;

  for (int kt = 0; kt < 8; ++kt) {
    __syncthreads();
#pragma unroll
    for (int j = 0; j < 4; ++j) {
      gll16(gA + (size_t)j * 8 * (DIM * 2), lA + j * 1024);
      gll16(gB + (size_t)j * 8 * (DIM * 2), lB + j * 1024);
    }
    gA += 128; gB += 128;
    __syncthreads();
#pragma unroll
    for (int c = 0; c < 8; c += 4) {                // logical chunk base (kk = c*8)
      const int po = ((c + jc) ^ cn7) << 3;         // swizzled element offset in row
      bf16x8 aF[4], bF[4];
#pragma unroll
      for (int mi = 0; mi < 4; ++mi)
        aF[mi] = *(const bf16x8*)&lsA[(wm * 64 + mi * 16 + cn) * 64 + po];
#pragma unroll
      for (int ni = 0; ni < 4; ++ni)
        bF[ni] = *(const bf16x8*)&lsB[(wn * 64 + ni * 16 + cn) * 64 + po];
#pragma unroll
      for (int mi = 0; mi < 4; ++mi)
#pragma unroll
        for (int ni = 0; ni < 4; ++ni)
          acc[mi][ni] = __builtin_amdgcn_mfma_f32_16x16x32_bf16(aF[mi], bF[ni], acc[mi][ni], 0, 0, 0);
    }
  }

  // ---- epilogue: per-wave 64x64 transpose through LDS (swizzled), coalesced stores ----
  __syncthreads();                                  // everyone done reading lsA/lsB
  ushort_t* area = ls + wave * 4096;                // 8 KB/wave: 64 rows x 64 cols
  float bv[4];
#pragma unroll
  for (int ni = 0; ni < 4; ++ni) bv[ni] = bvec[s * DIM + eBase + wn * 64 + ni * 16 + cn];
  const int jc4 = jc * 4;
#pragma unroll
  for (int mi = 0; mi < 4; ++mi)
#pragma unroll
    for (int ni = 0; ni < 4; ++ni)
#pragma unroll
      for (int r = 0; r < 4; ++r) {
        const int lr = mi * 16 + jc4 + r;           // local q row
        const int lc = ni * 16 + cn;                // local e col
        const int off = lr * 64 + (((lc >> 3) ^ (lr & 7)) << 3) + (lc & 7);
        area[off] = f2bf(acc[mi][ni][r] + bv[ni]);
      }
  __syncthreads();
  const int rr = lane >> 3;                         // 0..7: row within pass
  const int ch = lane & 7;                          // e-chunk
  const int physc = ch ^ rr;
  const size_t tqs = (size_t)s * (NQ * DIM);
#pragma unroll
  for (int pass = 0; pass < 8; ++pass) {
    const int lr = pass * 8 + rr;
    uint4 v = *(const uint4*)&area[lr * 64 + physc * 8];
    uint32_t wsv[4] = {v.x, v.y, v.z, v.w};
    float ss = 0.f;
#pragma unroll
    for (int i = 0; i < 4; ++i) {
      float lo = bf2f((ushort_t)(wsv[i] & 0xFFFFu));
      float hi = bf2f((ushort_t)(wsv[i] >> 16));
      ss += lo * lo + hi * hi;
    }
    ss += __shfl_xor(ss, 1, 64);
    ss += __shfl_xor(ss, 2, 64);
    ss += __shfl_xor(ss, 4, 64);
    const int q = qBase + wm * 64 + lr;
    *(uint4*)&tq[tqs + (size_t)q * DIM + eBase + wn * 64 + ch * 8] = v;
    if (ch == 0) atomicAdd(&sqq[s * NQ + q], ss);
  }
}

// ================= GEMM2 fused dist/mean/std — 2-wave 64x64 blocks, s-pair in-wave ======
// Block: 128 threads (2 waves), tile 64q x 64p, BK=64 (row=128B=8 chunks).
// Wave = 32q x 64p x 2 samples: B-fragments reused in-register across the pair
// (16 b128 reads feed 32 MFMAs -> 0.5 reads/MFMA). LDS 24 KB -> 4 blocks/CU.
// grid (64,16) q-fastest: adjacent blocks share L2-resident pb; A-sharers staggered.
__global__ __launch_bounds__(128, 2) void gemm_dist_kernel(const ushort_t* __restrict__ tq,
                                                           const ushort_t* __restrict__ pb,
                                                           const float* __restrict__ sqq,
                                                           const float* __restrict__ sqp,
                                                           float* __restrict__ out) {
  __shared__ __align__(16) ushort_t lsA[2 * 64 * 64];   // 16 KB: A(s0) | A(s1)
  __shared__ __align__(16) ushort_t lsB[64 * 64];       //  8 KB
  const int lane = threadIdx.x & 63;
  const int wave = threadIdx.x >> 6;   // 0..1: q offset 32*wave
  const int qBase = blockIdx.x * 64;
  const int pBase = blockIdx.y * 64;
  const int srow = lane >> 3;          // 0..7
  const int scol = ((lane & 7) ^ srow) * 16;   // swizzled global chunk (bytes)
  const int cn = lane & 15;
  const int cn7 = cn & 7;
  const int jc = lane >> 4;
  const int rq = jc * 4;
  const floatx4 fzero = {0.f, 0.f, 0.f, 0.f};
  // per-thread staging bases (wave covers rows wave*32 + g*8 + srow, g=0..3)
  const char* gAb = (const char*)tq + (size_t)(qBase + wave * 32 + srow) * (DIM * 2) + scol;
  const char* gBb = (const char*)pb + (size_t)(pBase + wave * 32 + srow) * (DIM * 2) + scol;
  char* lA0 = (char*)lsA + (wave * 32) * 128;
  char* lA1 = lA0 + 8192;
  char* lBw = (char*)lsB + (wave * 32) * 128;
  int po[2];
#pragma unroll
  for (int c = 0; c < 2; ++c) po[c] = ((c * 4 + jc) ^ cn7) << 3;

  float sum[2][4][4] = {};   // [mi][ni][r]
  float ssq[2][4][4] = {};
  float sqp_v[4];
#pragma unroll
  for (int ni = 0; ni < 4; ++ni) sqp_v[ni] = sqp[pBase + ni * 16 + cn];

  for (int s0 = 0; s0 < NS; s0 += 2) {
    floatx4 acc[2][2][4];    // [sp][mi][ni]
#pragma unroll
    for (int sp = 0; sp < 2; ++sp)
#pragma unroll
      for (int mi = 0; mi < 2; ++mi)
#pragma unroll
        for (int ni = 0; ni < 4; ++ni) acc[sp][mi][ni] = fzero;

    const char* gA0 = gAb + (size_t)s0 * (NQ * DIM * 2);
    const char* gA1 = gA0 + (size_t)(NQ * DIM * 2);
    const char* gBk = gBb;
    for (int kt = 0; kt < 8; ++kt) {
      __syncthreads();
#pragma unroll
      for (int g = 0; g < 4; ++g) {
        const size_t gRow = (size_t)g * 8 * (DIM * 2);
        gll16(gA0 + gRow, lA0 + g * 1024);
        gll16(gA1 + gRow, lA1 + g * 1024);
        gll16(gBk + gRow, lBw + g * 1024);
      }
      gA0 += 128; gA1 += 128; gBk += 128;
      __syncthreads();
#pragma unroll
      for (int c = 0; c < 2; ++c) {
        bf16x8 bF[4];
#pragma unroll
        for (int ni = 0; ni < 4; ++ni)
          bF[ni] = *(const bf16x8*)&lsB[(ni * 16 + cn) * 64 + po[c]];
#pragma unroll
        for (int sp = 0; sp < 2; ++sp) {
          bf16x8 aF[2];
#pragma unroll
          for (int mi = 0; mi < 2; ++mi)
            aF[mi] = *(const bf16x8*)&lsA[sp * 4096 + (wave * 32 + mi * 16 + cn) * 64 + po[c]];
#pragma unroll
          for (int mi = 0; mi < 2; ++mi)
#pragma unroll
            for (int ni = 0; ni < 4; ++ni)
              acc[sp][mi][ni] =
                  __builtin_amdgcn_mfma_f32_16x16x32_bf16(aF[mi], bF[ni], acc[sp][mi][ni], 0, 0, 0);
        }
      }
    }
    // fold both samples into running stats (ssq accumulates pre-sqrt sqd)
#pragma unroll
    for (int sp = 0; sp < 2; ++sp) {
      const int s = s0 + sp;
#pragma unroll
      for (int mi = 0; mi < 2; ++mi) {
        float4 aqv = *(const float4*)&sqq[s * NQ + qBase + wave * 32 + mi * 16 + rq];
        float aqa[4] = {aqv.x, aqv.y, aqv.z, aqv.w};
#pragma unroll
        for (int r = 0; r < 4; ++r) {
          float aq = aqa[r];
#pragma unroll
          for (int ni = 0; ni < 4; ++ni) {
            float sqd = fmaxf(fmaf(-2.0f, acc[sp][mi][ni][r], aq + sqp_v[ni]), 1e-12f);
            sum[mi][ni][r] += sqrtf(sqd);
            ssq[mi][ni][r] += sqd;
          }
        }
      }
    }
  }
#pragma unroll
  for (int mi = 0; mi < 2; ++mi)
#pragma unroll
    for (int ni = 0; ni < 4; ++ni)
#pragma unroll
      for (int r = 0; r < 4; ++r) {
        int q = qBase + wave * 32 + mi * 16 + rq + r;
        int p = pBase + ni * 16 + cn;
        float sm = sum[mi][ni][r];
        float mean = sm * 0.1f;
        float var = (ssq[mi][ni][r] - sm * sm * 0.1f) * (1.0f / 9.0f);
        out[(size_t)q * NP + p] = mean;
        out[(size_t)NQ * NP + (size_t)q * NP + p] = sqrtf(fmaxf(var, 0.0f));
      }
}

// ================= launch =================
extern "C" void kernel_launch(void* const* d_in, const int* in_sizes, int n_in,
                              void* d_out, int out_size, void* d_ws, size_t ws_size,
                              hipStream_t stream) {
  const float* qf   = (const float*)d_in[0];
  const float* pf   = (const float*)d_in[1];
  const float* wmu  = (const float*)d_in[2];
  const float* wrho = (const float*)d_in[3];
  const float* bmu  = (const float*)d_in[4];
  const float* brho = (const float*)d_in[5];
  float* out = (float*)d_out;
  char* ws = (char*)d_ws;
  ushort_t* wt   = (ushort_t*)(ws);              //  5,242,880  W^T bf16 [s][e][k]
  ushort_t* qb   = (ushort_t*)(ws + 5242880);    //  4,194,304  query bf16
  ushort_t* pb   = (ushort_t*)(ws + 9437184);    //  1,048,576  proto bf16
  float*    bvec = (float*)   (ws + 10485760);   //     20,480  bias samples
  float*    sqp  = (float*)   (ws + 10506240);   //      4,096  ||p||^2
  ushort_t* tq   = (ushort_t*)(ws + 10510336);   // 41,943,040  tq bf16 [s][q][e]
  float*    sqq  = (float*)   (ws + 52453376);   //    163,840  ||tq||^2 (atomic-accumulated)

  uint32_t kw0, kw1, kb0, kb1;
  threefry2x32(0u, 42u, 0u, 0u, &kw0, &kw1);
  threefry2x32(0u, 42u, 0u, 1u, &kb0, &kb1);

  hipLaunchKernelGGL(prep_kernel, dim3(12724), dim3(256), 0, stream,
                     qf, pf, wmu, wrho, bmu, brho, wt, qb, pb, sqp, bvec, sqq,
                     kw0, kw1, kb0, kb1);
  hipLaunchKernelGGL(gemm_tq_kernel, dim3(32, 4, 10), dim3(256), 0, stream, qb, wt, bvec, tq, sqq);
  hipLaunchKernelGGL(gemm_dist_kernel, dim3(64, 16), dim3(128), 0, stream, tq, pb, sqq, sqp, out);
}

// Round 9
// 200.042 us; speedup vs baseline: 1.2255x; 1.0098x over previous
//
#include <hip/hip_runtime.h>
#include <stdint.h>

#define NS 10
#define DIM 512
#define NQ 4096
#define NP 1024

typedef unsigned short ushort_t;
typedef __bf16 bf16el_t;
typedef bf16el_t bf16x8 __attribute__((ext_vector_type(8)));
typedef float floatx4 __attribute__((ext_vector_type(4)));

// ================= threefry2x32-20 (JAX-compatible, partitionable path) =================
__host__ __device__ __forceinline__ uint32_t rotl32(uint32_t x, int r) {
  return (x << r) | (x >> (32 - r));
}

__host__ __device__ __forceinline__ void threefry2x32(uint32_t k0, uint32_t k1,
                                                      uint32_t x0, uint32_t x1,
                                                      uint32_t* o0, uint32_t* o1) {
  uint32_t ks2 = k0 ^ k1 ^ 0x1BD11BDAu;
  x0 += k0; x1 += k1;
#define TF_R(r) { x0 += x1; x1 = rotl32(x1, r); x1 ^= x0; }
  TF_R(13) TF_R(15) TF_R(26) TF_R(6)   x0 += k1;  x1 += ks2 + 1u;
  TF_R(17) TF_R(29) TF_R(16) TF_R(24)  x0 += ks2; x1 += k0 + 2u;
  TF_R(13) TF_R(15) TF_R(26) TF_R(6)   x0 += k0;  x1 += k1 + 3u;
  TF_R(17) TF_R(29) TF_R(16) TF_R(24)  x0 += k1;  x1 += ks2 + 4u;
  TF_R(13) TF_R(15) TF_R(26) TF_R(6)   x0 += ks2; x1 += k0 + 5u;
#undef TF_R
  *o0 = x0; *o1 = x1;
}

__device__ __forceinline__ uint32_t jax_random_bits(uint32_t k0, uint32_t k1, uint32_t idx) {
  uint32_t o0, o1;
  threefry2x32(k0, k1, 0u, idx, &o0, &o1);
  return o0 ^ o1;
}

// XLA ErfInv32 (Giles polynomial)
__device__ __forceinline__ float erfinvf_xla(float x) {
  float w = -log1pf(-x * x);
  float p;
  if (w < 5.0f) {
    w -= 2.5f;
    p = 2.81022636e-08f;
    p = fmaf(p, w, 3.43273939e-07f);
    p = fmaf(p, w, -3.5233877e-06f);
    p = fmaf(p, w, -4.39150654e-06f);
    p = fmaf(p, w, 0.00021858087f);
    p = fmaf(p, w, -0.00125372503f);
    p = fmaf(p, w, -0.00417768164f);
    p = fmaf(p, w, 0.246640727f);
    p = fmaf(p, w, 1.50140941f);
  } else {
    w = sqrtf(w) - 3.0f;
    p = -0.000200214257f;
    p = fmaf(p, w, 0.000100950558f);
    p = fmaf(p, w, 0.00134934322f);
    p = fmaf(p, w, -0.00367342844f);
    p = fmaf(p, w, 0.00573950773f);
    p = fmaf(p, w, -0.0076224613f);
    p = fmaf(p, w, 0.00943887047f);
    p = fmaf(p, w, 1.00167406f);
    p = fmaf(p, w, 2.83297682f);
  }
  return p * x;
}

__device__ __forceinline__ float jax_bits_to_normal(uint32_t bits) {
  float f = __uint_as_float((bits >> 9) | 0x3F800000u) - 1.0f;
  float u = f * 2.0f - 0.99999994f;
  u = fmaxf(u, -0.99999994f);
  return 1.41421356f * erfinvf_xla(u);
}

__device__ __forceinline__ float softplusf(float x) { return log1pf(expf(x)); }

__device__ __forceinline__ float bf2f(ushort_t u) {
  return __uint_as_float(((uint32_t)u) << 16);
}
__device__ __forceinline__ ushort_t f2bf(float f) {
  uint32_t u = __float_as_uint(f);
  u += 0x7FFFu + ((u >> 16) & 1u);
  return (ushort_t)(u >> 16);
}

// async global->LDS, 16B per lane. LDS dst = wave-uniform base + lane*16.
__device__ __forceinline__ void gll16(const void* g, void* l) {
  __builtin_amdgcn_global_load_lds(
      (const __attribute__((address_space(1))) uint32_t*)g,
      (__attribute__((address_space(3))) uint32_t*)l, 16, 0, 0);
}

// ================= fused prep: gen_w | cvt_q | cvt_p+sqp | gen_b | zero sqq ==============
__global__ __launch_bounds__(256) void prep_kernel(const float* __restrict__ qf,
                                                   const float* __restrict__ pf,
                                                   const float* __restrict__ wmu,
                                                   const float* __restrict__ wrho,
                                                   const float* __restrict__ bmu,
                                                   const float* __restrict__ brho,
                                                   ushort_t* __restrict__ wt,
                                                   ushort_t* __restrict__ qb,
                                                   ushort_t* __restrict__ pb,
                                                   float* __restrict__ sqp,
                                                   float* __restrict__ bvec,
                                                   float* __restrict__ sqq,
                                                   uint32_t kw0, uint32_t kw1,
                                                   uint32_t kb0, uint32_t kb1) {
  const int blk = blockIdx.x;
  const int tid = threadIdx.x;
  if (blk < 10240) {                     // ---- gen_w: wt[s][e][k], 2,621,440 elems ----
    uint32_t t = blk * 256u + tid;
    uint32_t s = t >> 18;
    uint32_t r = t & 0x3FFFFu;
    uint32_t e = r >> 9;
    uint32_t k = r & 511u;
    uint32_t eps_idx = (s << 18) | (k << 9) | e;    // JAX order [s][k][e]
    uint32_t bits = jax_random_bits(kw0, kw1, eps_idx);
    float n = jax_bits_to_normal(bits);
    uint32_t mi = (k << 9) | e;
    float w = wmu[mi] + softplusf(wrho[mi]) * n;
    wt[t] = f2bf(w);
  } else if (blk < 12288) {              // ---- cvt_q: 2,097,152 floats ----
    int i = ((blk - 10240) * 256 + tid) * 4;
    float4 v = *(const float4*)&qf[i];
    uint2 r;
    r.x = (uint32_t)f2bf(v.x) | ((uint32_t)f2bf(v.y) << 16);
    r.y = (uint32_t)f2bf(v.z) | ((uint32_t)f2bf(v.w) << 16);
    *(uint2*)&qb[i] = r;
  } else if (blk < 12544) {              // ---- cvt_p + sqp: 4 protos / block ----
    int p = (blk - 12288) * 4 + (tid >> 6);
    int lane = tid & 63;
    const float* src = pf + p * DIM + lane * 8;
    float4 a = *(const float4*)src;
    float4 b = *(const float4*)(src + 4);
    float vals[8] = {a.x, a.y, a.z, a.w, b.x, b.y, b.z, b.w};
    ushort_t o[8];
    float ss = 0.f;
#pragma unroll
    for (int i = 0; i < 8; ++i) {
      o[i] = f2bf(vals[i]);
      float f = bf2f(o[i]);
      ss += f * f;
    }
    *(uint4*)&pb[p * DIM + lane * 8] = *(const uint4*)o;
#pragma unroll
    for (int off = 32; off; off >>= 1) ss += __shfl_xor(ss, off, 64);
    if (lane == 0) sqp[p] = ss;
  } else if (blk < 12564) {              // ---- gen_b: 5120 ----
    uint32_t t2 = (blk - 12544) * 256u + tid;
    uint32_t e = t2 & 511u;
    uint32_t bits = jax_random_bits(kb0, kb1, t2);
    float n = jax_bits_to_normal(bits);
    bvec[t2] = bmu[e] + softplusf(brho[e]) * n;
  } else {                               // ---- zero sqq: 40960 floats ----
    int i = (blk - 12564) * 256 + tid;
    sqq[i] = 0.f;
  }
}

// ================= GEMM1: tq[s] = q @ W_s + b_s (R4-proven, unchanged) =================
__global__ __launch_bounds__(256) void gemm_tq_kernel(const ushort_t* __restrict__ qb,
                                                      const ushort_t* __restrict__ wt,
                                                      const float* __restrict__ bvec,
                                                      ushort_t* __restrict__ tq,
                                                      float* __restrict__ sqq) {
  __shared__ __align__(16) ushort_t ls[2 * 128 * 64];   // 32 KB: lsA | lsB, reused by epilogue
  ushort_t* lsA = ls;
  ushort_t* lsB = ls + 128 * 64;
  const int lane = threadIdx.x & 63;
  const int wave = threadIdx.x >> 6;
  const int wm = wave >> 1, wn = wave & 1;   // 2x2 wave grid, 64x64 each
  const int qBase = blockIdx.x * 128;
  const int eBase = blockIdx.y * 128;
  const int s = blockIdx.z;
  const ushort_t* wbase = wt + (size_t)s * (DIM * DIM);  // [e][k]
  const int srow = lane >> 3;                       // 0..7
  const int scol = ((lane & 7) ^ srow) * 16;        // swizzled global chunk (bytes)
  const char* gA = (const char*)qb + (size_t)(qBase + wave * 32 + srow) * (DIM * 2) + scol;
  const char* gB = (const char*)wbase + (size_t)(eBase + wave * 32 + srow) * (DIM * 2) + scol;
  char* lA = (char*)&lsA[wave * 32 * 64];
  char* lB = (char*)&lsB[wave * 32 * 64];
  const int cn = lane & 15;
  const int cn7 = cn & 7;
  const int jc = lane >> 4;                         // 0..3
  const floatx4 fzero = {0.f, 0.f, 0.f, 0.f};
  floatx4 acc[4][4];
#pragma unroll
  for (int mi = 0; mi < 4; ++mi)
#pragma unroll
    for (int ni = 0; ni < 4; ++ni) acc[mi][ni] = fzero;

  for (int kt = 0; kt < 8; ++kt) {
    __syncthreads();
#pragma unroll
    for (int j = 0; j < 4; ++j) {
      gll16(gA + (size_t)j * 8 * (DIM * 2), lA + j * 1024);
      gll16(gB + (size_t)j * 8 * (DIM * 2), lB + j * 1024);
    }
    gA += 128; gB += 128;
    __syncthreads();
#pragma unroll
    for (int c = 0; c < 8; c += 4) {                // logical chunk base (kk = c*8)
      const int po = ((c + jc) ^ cn7) << 3;         // swizzled element offset in row
      bf16x8 aF[4], bF[4];
#pragma unroll
      for (int mi = 0; mi < 4; ++mi)
        aF[mi] = *(const bf16x8*)&lsA[(wm * 64 + mi * 16 + cn) * 64 + po];
#pragma unroll
      for (int ni = 0; ni < 4; ++ni)
        bF[ni] = *(const bf16x8*)&lsB[(wn * 64 + ni * 16 + cn) * 64 + po];
#pragma unroll
      for (int mi = 0; mi < 4; ++mi)
#pragma unroll
        for (int ni = 0; ni < 4; ++ni)
          acc[mi][ni] = __builtin_amdgcn_mfma_f32_16x16x32_bf16(aF[mi], bF[ni], acc[mi][ni], 0, 0, 0);
    }
  }

  // ---- epilogue: per-wave 64x64 transpose through LDS (swizzled), coalesced stores ----
  __syncthreads();                                  // everyone done reading lsA/lsB
  ushort_t* area = ls + wave * 4096;                // 8 KB/wave: 64 rows x 64 cols
  float bv[4];
#pragma unroll
  for (int ni = 0; ni < 4; ++ni) bv[ni] = bvec[s * DIM + eBase + wn * 64 + ni * 16 + cn];
  const int jc4 = jc * 4;
#pragma unroll
  for (int mi = 0; mi < 4; ++mi)
#pragma unroll
    for (int ni = 0; ni < 4; ++ni)
#pragma unroll
      for (int r = 0; r < 4; ++r) {
        const int lr = mi * 16 + jc4 + r;           // local q row
        const int lc = ni * 16 + cn;                // local e col
        const int off = lr * 64 + (((lc >> 3) ^ (lr & 7)) << 3) + (lc & 7);
        area[off] = f2bf(acc[mi][ni][r] + bv[ni]);
      }
  __syncthreads();
  const int rr = lane >> 3;                         // 0..7: row within pass
  const int ch = lane & 7;                          // e-chunk
  const int physc = ch ^ rr;
  const size_t tqs = (size_t)s * (NQ * DIM);
#pragma unroll
  for (int pass = 0; pass < 8; ++pass) {
    const int lr = pass * 8 + rr;
    uint4 v = *(const uint4*)&area[lr * 64 + physc * 8];
    uint32_t wsv[4] = {v.x, v.y, v.z, v.w};
    float ss = 0.f;
#pragma unroll
    for (int i = 0; i < 4; ++i) {
      float lo = bf2f((ushort_t)(wsv[i] & 0xFFFFu));
      float hi = bf2f((ushort_t)(wsv[i] >> 16));
      ss += lo * lo + hi * hi;
    }
    ss += __shfl_xor(ss, 1, 64);
    ss += __shfl_xor(ss, 2, 64);
    ss += __shfl_xor(ss, 4, 64);
    const int q = qBase + wm * 64 + lr;
    *(uint4*)&tq[tqs + (size_t)q * DIM + eBase + wn * 64 + ch * 8] = v;
    if (ch == 0) atomicAdd(&sqq[s * NQ + q], ss);
  }
}

// ================= GEMM2 fused dist/mean/std — 64q x 128p, 4 waves, s-pairs ==============
// Block: 256 threads (4 waves of 32q x 64p), BK=64, s-pairs with in-register B reuse.
// LDS 32 KB (A 2x8 KB + B 16 KB) -> 2 blocks/CU (under the 48 KB cliff), 8 waves/CU.
// A staged once per block per kt (shared by both wave-rows) -> A traffic halved vs 64p tile.
// grid (64,8) q-fastest (proven L3-friendly; avoids R6 cross-XCD co-fetch).
__global__ __launch_bounds__(256, 2) void gemm_dist_kernel(const ushort_t* __restrict__ tq,
                                                           const ushort_t* __restrict__ pb,
                                                           const float* __restrict__ sqq,
                                                           const float* __restrict__ sqp,
                                                           float* __restrict__ out) {
  __shared__ __align__(16) ushort_t lsA[2 * 64 * 64];   // 16 KB: A(s0) | A(s1), row=128B
  __shared__ __align__(16) ushort_t lsB[128 * 64];      // 16 KB
  const int lane = threadIdx.x & 63;
  const int wave = threadIdx.x >> 6;   // 0..3
  const int wm = wave >> 1;            // q offset 32*wm
  const int wn = wave & 1;             // p offset 64*wn
  const int qBase = blockIdx.x * 64;
  const int pBase = blockIdx.y * 128;
  const int srow = lane >> 3;          // 0..7
  const int scol = ((lane & 7) ^ srow) * 16;   // swizzled global chunk (bytes)
  const int cn = lane & 15;
  const int cn7 = cn & 7;
  const int jc = lane >> 4;
  const int rq = jc * 4;
  const floatx4 fzero = {0.f, 0.f, 0.f, 0.f};
  // staging: A 64 rows -> wave covers rows [wave*16, wave*16+16) via 2 calls of 8 rows;
  //          B 128 rows -> wave covers rows [wave*32, wave*32+32) via 4 calls of 8 rows.
  const char* gAb = (const char*)tq + (size_t)(qBase + wave * 16 + srow) * (DIM * 2) + scol;
  const char* gBb = (const char*)pb + (size_t)(pBase + wave * 32 + srow) * (DIM * 2) + scol;
  char* lA0 = (char*)lsA + wave * 2048;          // into A(s0) half
  char* lA1 = (char*)lsA + 8192 + wave * 2048;   // into A(s1) half
  char* lBw = (char*)lsB + wave * 4096;
  int po[2];
#pragma unroll
  for (int c = 0; c < 2; ++c) po[c] = ((c * 4 + jc) ^ cn7) << 3;

  float sum[2][4][4] = {};   // [mi][ni][r]
  float ssq[2][4][4] = {};
  float sqp_v[4];
#pragma unroll
  for (int ni = 0; ni < 4; ++ni) sqp_v[ni] = sqp[pBase + wn * 64 + ni * 16 + cn];

  for (int s0 = 0; s0 < NS; s0 += 2) {
    floatx4 acc[2][2][4];    // [sp][mi][ni]
#pragma unroll
    for (int sp = 0; sp < 2; ++sp)
#pragma unroll
      for (int mi = 0; mi < 2; ++mi)
#pragma unroll
        for (int ni = 0; ni < 4; ++ni) acc[sp][mi][ni] = fzero;

    const char* gA0 = gAb + (size_t)s0 * (NQ * DIM * 2);
    const char* gA1 = gA0 + (size_t)(NQ * DIM * 2);
    const char* gBk = gBb;
    for (int kt = 0; kt < 8; ++kt) {
      __syncthreads();
#pragma unroll
      for (int j = 0; j < 2; ++j) {
        const size_t gRow = (size_t)j * 8 * (DIM * 2);
        gll16(gA0 + gRow, lA0 + j * 1024);
        gll16(gA1 + gRow, lA1 + j * 1024);
      }
#pragma unroll
      for (int j = 0; j < 4; ++j)
        gll16(gBk + (size_t)j * 8 * (DIM * 2), lBw + j * 1024);
      gA0 += 128; gA1 += 128; gBk += 128;
      __syncthreads();
#pragma unroll
      for (int c = 0; c < 2; ++c) {
        bf16x8 bF[4];
#pragma unroll
        for (int ni = 0; ni < 4; ++ni)
          bF[ni] = *(const bf16x8*)&lsB[(wn * 64 + ni * 16 + cn) * 64 + po[c]];
#pragma unroll
        for (int sp = 0; sp < 2; ++sp) {
          bf16x8 aF[2];
#pragma unroll
          for (int mi = 0; mi < 2; ++mi)
            aF[mi] = *(const bf16x8*)&lsA[sp * 4096 + (wm * 32 + mi * 16 + cn) * 64 + po[c]];
#pragma unroll
          for (int mi = 0; mi < 2; ++mi)
#pragma unroll
            for (int ni = 0; ni < 4; ++ni)
              acc[sp][mi][ni] =
                  __builtin_amdgcn_mfma_f32_16x16x32_bf16(aF[mi], bF[ni], acc[sp][mi][ni], 0, 0, 0);
        }
      }
    }
    // fold both samples into running stats (ssq accumulates pre-sqrt sqd)
#pragma unroll
    for (int sp = 0; sp < 2; ++sp) {
      const int s = s0 + sp;
#pragma unroll
      for (int mi = 0; mi < 2; ++mi) {
        float4 aqv = *(const float4*)&sqq[s * NQ + qBase + wm * 32 + mi * 16 + rq];
        float aqa[4] = {aqv.x, aqv.y, aqv.z, aqv.w};
#pragma unroll
        for (int r = 0; r < 4; ++r) {
          float aq = aqa[r];
#pragma unroll
          for (int ni = 0; ni < 4; ++ni) {
            float sqd = fmaxf(fmaf(-2.0f, acc[sp][mi][ni][r], aq + sqp_v[ni]), 1e-12f);
            sum[mi][ni][r] += sqrtf(sqd);
            ssq[mi][ni][r] += sqd;
          }
        }
      }
    }
  }
#pragma unroll
  for (int mi = 0; mi < 2; ++mi)
#pragma unroll
    for (int ni = 0; ni < 4; ++ni)
#pragma unroll
      for (int r = 0; r < 4; ++r) {
        int q = qBase + wm * 32 + mi * 16 + rq + r;
        int p = pBase + wn * 64 + ni * 16 + cn;
        float sm = sum[mi][ni][r];
        float mean = sm * 0.1f;
        float var = (ssq[mi][ni][r] - sm * sm * 0.1f) * (1.0f / 9.0f);
        out[(size_t)q * NP + p] = mean;
        out[(size_t)NQ * NP + (size_t)q * NP + p] = sqrtf(fmaxf(var, 0.0f));
      }
}

// ================= launch =================
extern "C" void kernel_launch(void* const* d_in, const int* in_sizes, int n_in,
                              void* d_out, int out_size, void* d_ws, size_t ws_size,
                              hipStream_t stream) {
  const float* qf   = (const float*)d_in[0];
  const float* pf   = (const float*)d_in[1];
  const float* wmu  = (const float*)d_in[2];
  const float* wrho = (const float*)d_in[3];
  const float* bmu  = (const float*)d_in[4];
  const float* brho = (const float*)d_in[5];
  float* out = (float*)d_out;
  char* ws = (char*)d_ws;
  ushort_t* wt   = (ushort_t*)(ws);              //  5,242,880  W^T bf16 [s][e][k]
  ushort_t* qb   = (ushort_t*)(ws + 5242880);    //  4,194,304  query bf16
  ushort_t* pb   = (ushort_t*)(ws + 9437184);    //  1,048,576  proto bf16
  float*    bvec = (float*)   (ws + 10485760);   //     20,480  bias samples
  float*    sqp  = (float*)   (ws + 10506240);   //      4,096  ||p||^2
  ushort_t* tq   = (ushort_t*)(ws + 10510336);   // 41,943,040  tq bf16 [s][q][e]
  float*    sqq  = (float*)   (ws + 52453376);   //    163,840  ||tq||^2 (atomic-accumulated)

  uint32_t kw0, kw1, kb0, kb1;
  threefry2x32(0u, 42u, 0u, 0u, &kw0, &kw1);
  threefry2x32(0u, 42u, 0u, 1u, &kb0, &kb1);

  hipLaunchKernelGGL(prep_kernel, dim3(12724), dim3(256), 0, stream,
                     qf, pf, wmu, wrho, bmu, brho, wt, qb, pb, sqp, bvec, sqq,
                     kw0, kw1, kb0, kb1);
  hipLaunchKernelGGL(gemm_tq_kernel, dim3(32, 4, 10), dim3(256), 0, stream, qb, wt, bvec, tq, sqq);
  hipLaunchKernelGGL(gemm_dist_kernel, dim3(64, 8), dim3(256), 0, stream, tq, pb, sqq, sqp, out);
}

// Round 10
// 197.124 us; speedup vs baseline: 1.2437x; 1.0148x over previous
//
#include <hip/hip_runtime.h>
#include <stdint.h>

#define NS 10
#define DIM 512
#define NQ 4096
#define NP 1024

typedef unsigned short ushort_t;
typedef __bf16 bf16el_t;
typedef bf16el_t bf16x8 __attribute__((ext_vector_type(8)));
typedef float floatx4 __attribute__((ext_vector_type(4)));

// ================= threefry2x32-20 (JAX-compatible, partitionable path) =================
__host__ __device__ __forceinline__ uint32_t rotl32(uint32_t x, int r) {
  return (x << r) | (x >> (32 - r));
}

__host__ __device__ __forceinline__ void threefry2x32(uint32_t k0, uint32_t k1,
                                                      uint32_t x0, uint32_t x1,
                                                      uint32_t* o0, uint32_t* o1) {
  uint32_t ks2 = k0 ^ k1 ^ 0x1BD11BDAu;
  x0 += k0; x1 += k1;
#define TF_R(r) { x0 += x1; x1 = rotl32(x1, r); x1 ^= x0; }
  TF_R(13) TF_R(15) TF_R(26) TF_R(6)   x0 += k1;  x1 += ks2 + 1u;
  TF_R(17) TF_R(29) TF_R(16) TF_R(24)  x0 += ks2; x1 += k0 + 2u;
  TF_R(13) TF_R(15) TF_R(26) TF_R(6)   x0 += k0;  x1 += k1 + 3u;
  TF_R(17) TF_R(29) TF_R(16) TF_R(24)  x0 += k1;  x1 += ks2 + 4u;
  TF_R(13) TF_R(15) TF_R(26) TF_R(6)   x0 += ks2; x1 += k0 + 5u;
#undef TF_R
  *o0 = x0; *o1 = x1;
}

__device__ __forceinline__ uint32_t jax_random_bits(uint32_t k0, uint32_t k1, uint32_t idx) {
  uint32_t o0, o1;
  threefry2x32(k0, k1, 0u, idx, &o0, &o1);
  return o0 ^ o1;
}

// XLA ErfInv32 (Giles polynomial)
__device__ __forceinline__ float erfinvf_xla(float x) {
  float w = -log1pf(-x * x);
  float p;
  if (w < 5.0f) {
    w -= 2.5f;
    p = 2.81022636e-08f;
    p = fmaf(p, w, 3.43273939e-07f);
    p = fmaf(p, w, -3.5233877e-06f);
    p = fmaf(p, w, -4.39150654e-06f);
    p = fmaf(p, w, 0.00021858087f);
    p = fmaf(p, w, -0.00125372503f);
    p = fmaf(p, w, -0.00417768164f);
    p = fmaf(p, w, 0.246640727f);
    p = fmaf(p, w, 1.50140941f);
  } else {
    w = sqrtf(w) - 3.0f;
    p = -0.000200214257f;
    p = fmaf(p, w, 0.000100950558f);
    p = fmaf(p, w, 0.00134934322f);
    p = fmaf(p, w, -0.00367342844f);
    p = fmaf(p, w, 0.00573950773f);
    p = fmaf(p, w, -0.0076224613f);
    p = fmaf(p, w, 0.00943887047f);
    p = fmaf(p, w, 1.00167406f);
    p = fmaf(p, w, 2.83297682f);
  }
  return p * x;
}

__device__ __forceinline__ float jax_bits_to_normal(uint32_t bits) {
  float f = __uint_as_float((bits >> 9) | 0x3F800000u) - 1.0f;
  float u = f * 2.0f - 0.99999994f;
  u = fmaxf(u, -0.99999994f);
  return 1.41421356f * erfinvf_xla(u);
}

__device__ __forceinline__ float softplusf(float x) { return log1pf(expf(x)); }

__device__ __forceinline__ float bf2f(ushort_t u) {
  return __uint_as_float(((uint32_t)u) << 16);
}
__device__ __forceinline__ ushort_t f2bf(float f) {
  uint32_t u = __float_as_uint(f);
  u += 0x7FFFu + ((u >> 16) & 1u);
  return (ushort_t)(u >> 16);
}

// async global->LDS, 16B per lane. LDS dst = wave-uniform base + lane*16.
__device__ __forceinline__ void gll16(const void* g, void* l) {
  __builtin_amdgcn_global_load_lds(
      (const __attribute__((address_space(1))) uint32_t*)g,
      (__attribute__((address_space(3))) uint32_t*)l, 16, 0, 0);
}

// ================= fused prep: gen_w(tiled) | cvt_q | cvt_p+sqp | gen_b | zero sqq =======
// gen_w: 64x64 (k,e) tiles. Coalesced float4 reads of wmu/wrho rows, compute w,
// XOR-swizzled LDS transpose, coalesced 16B stores of wt[s][e][k] rows.
__global__ __launch_bounds__(256) void prep_kernel(const float* __restrict__ qf,
                                                   const float* __restrict__ pf,
                                                   const float* __restrict__ wmu,
                                                   const float* __restrict__ wrho,
                                                   const float* __restrict__ bmu,
                                                   const float* __restrict__ brho,
                                                   ushort_t* __restrict__ wt,
                                                   ushort_t* __restrict__ qb,
                                                   ushort_t* __restrict__ pb,
                                                   float* __restrict__ sqp,
                                                   float* __restrict__ bvec,
                                                   float* __restrict__ sqq,
                                                   uint32_t kw0, uint32_t kw1,
                                                   uint32_t kb0, uint32_t kb1) {
  __shared__ __align__(16) ushort_t lsW[64 * 64];   // 8 KB transpose tile
  const int blk = blockIdx.x;
  const int tid = threadIdx.x;
  if (blk < 640) {                       // ---- gen_w: 64x64 tiles, (s, kt, et) ----
    const int s = blk >> 6;
    const int rem = blk & 63;
    const int k0 = (rem >> 3) * 64;
    const int e0 = (rem & 7) * 64;
    const int r = tid >> 2;              // 0..63: local k row
    const int ch = tid & 3;              // 16-float e chunk
    const int kg = k0 + r;
    const int eg = e0 + ch * 16;
    const float* mup = wmu + kg * DIM + eg;
    const float* rhop = wrho + kg * DIM + eg;
    __align__(16) ushort_t wv[16];
#pragma unroll
    for (int v = 0; v < 4; ++v) {
      float4 m4 = *(const float4*)(mup + v * 4);
      float4 r4 = *(const float4*)(rhop + v * 4);
      float ms[4] = {m4.x, m4.y, m4.z, m4.w};
      float rs[4] = {r4.x, r4.y, r4.z, r4.w};
#pragma unroll
      for (int u = 0; u < 4; ++u) {
        uint32_t e = (uint32_t)(eg + v * 4 + u);
        uint32_t eps_idx = ((uint32_t)s << 18) | ((uint32_t)kg << 9) | e;  // JAX [s][k][e]
        float n = jax_bits_to_normal(jax_random_bits(kw0, kw1, eps_idx));
        wv[v * 4 + u] = f2bf(ms[u] + softplusf(rs[u]) * n);
      }
    }
    // swizzled store into [k][e] tile: element (r,e) at r*64 + ((e>>3 ^ (r&7))<<3) + (e&7)
    ushort_t* lrow = lsW + r * 64;
    *(uint4*)&lrow[((2 * ch) ^ (r & 7)) << 3]     = *(const uint4*)&wv[0];
    *(uint4*)&lrow[((2 * ch + 1) ^ (r & 7)) << 3] = *(const uint4*)&wv[8];
    __syncthreads();
    // transpose-read: output row e (64 k's = 128 B); thread -> (er, kc)
    const int er = tid >> 2;
    const int kc = tid & 3;
    __align__(16) ushort_t ov[16];
#pragma unroll
    for (int j = 0; j < 16; ++j) {
      int k = kc * 16 + j;
      ov[j] = lsW[k * 64 + ((((er >> 3) ^ (k & 7)) << 3)) + (er & 7)];
    }
    ushort_t* orow = wt + (size_t)s * (DIM * DIM) + (size_t)(e0 + er) * DIM + k0 + kc * 16;
    *(uint4*)&orow[0] = *(const uint4*)&ov[0];
    *(uint4*)&orow[8] = *(const uint4*)&ov[8];
  } else if (blk < 2688) {               // ---- cvt_q: 2,097,152 floats ----
    int i = ((blk - 640) * 256 + tid) * 4;
    float4 v = *(const float4*)&qf[i];
    uint2 r;
    r.x = (uint32_t)f2bf(v.x) | ((uint32_t)f2bf(v.y) << 16);
    r.y = (uint32_t)f2bf(v.z) | ((uint32_t)f2bf(v.w) << 16);
    *(uint2*)&qb[i] = r;
  } else if (blk < 2944) {               // ---- cvt_p + sqp: 4 protos / block ----
    int p = (blk - 2688) * 4 + (tid >> 6);
    int lane = tid & 63;
    const float* src = pf + p * DIM + lane * 8;
    float4 a = *(const float4*)src;
    float4 b = *(const float4*)(src + 4);
    float vals[8] = {a.x, a.y, a.z, a.w, b.x, b.y, b.z, b.w};
    ushort_t o[8];
    float ss = 0.f;
#pragma unroll
    for (int i = 0; i < 8; ++i) {
      o[i] = f2bf(vals[i]);
      float f = bf2f(o[i]);
      ss += f * f;
    }
    *(uint4*)&pb[p * DIM + lane * 8] = *(const uint4*)o;
#pragma unroll
    for (int off = 32; off; off >>= 1) ss += __shfl_xor(ss, off, 64);
    if (lane == 0) sqp[p] = ss;
  } else if (blk < 2964) {               // ---- gen_b: 5120 ----
    uint32_t t2 = (blk - 2944) * 256u + tid;
    uint32_t e = t2 & 511u;
    uint32_t bits = jax_random_bits(kb0, kb1, t2);
    float n = jax_bits_to_normal(bits);
    bvec[t2] = bmu[e] + softplusf(brho[e]) * n;
  } else {                               // ---- zero sqq: 40960 floats ----
    int i = (blk - 2964) * 256 + tid;
    sqq[i] = 0.f;
  }
}

// ================= GEMM1: tq[s] = q @ W_s + b_s (R4-proven, unchanged) =================
__global__ __launch_bounds__(256) void gemm_tq_kernel(const ushort_t* __restrict__ qb,
                                                      const ushort_t* __restrict__ wt,
                                                      const float* __restrict__ bvec,
                                                      ushort_t* __restrict__ tq,
                                                      float* __restrict__ sqq) {
  __shared__ __align__(16) ushort_t ls[2 * 128 * 64];   // 32 KB: lsA | lsB, reused by epilogue
  ushort_t* lsA = ls;
  ushort_t* lsB = ls + 128 * 64;
  const int lane = threadIdx.x & 63;
  const int wave = threadIdx.x >> 6;
  const int wm = wave >> 1, wn = wave & 1;   // 2x2 wave grid, 64x64 each
  const int qBase = blockIdx.x * 128;
  const int eBase = blockIdx.y * 128;
  const int s = blockIdx.z;
  const ushort_t* wbase = wt + (size_t)s * (DIM * DIM);  // [e][k]
  const int srow = lane >> 3;                       // 0..7
  const int scol = ((lane & 7) ^ srow) * 16;        // swizzled global chunk (bytes)
  const char* gA = (const char*)qb + (size_t)(qBase + wave * 32 + srow) * (DIM * 2) + scol;
  const char* gB = (const char*)wbase + (size_t)(eBase + wave * 32 + srow) * (DIM * 2) + scol;
  char* lA = (char*)&lsA[wave * 32 * 64];
  char* lB = (char*)&lsB[wave * 32 * 64];
  const int cn = lane & 15;
  const int cn7 = cn & 7;
  const int jc = lane >> 4;                         // 0..3
  const floatx4 fzero = {0.f, 0.f, 0.f, 0.f};
  floatx4 acc[4][4];
#pragma unroll
  for (int mi = 0; mi < 4; ++mi)
#pragma unroll
    for (int ni = 0; ni < 4; ++ni) acc[mi][ni] = fzero;

  for (int kt = 0; kt < 8; ++kt) {
    __syncthreads();
#pragma unroll
    for (int j = 0; j < 4; ++j) {
      gll16(gA + (size_t)j * 8 * (DIM * 2), lA + j * 1024);
      gll16(gB + (size_t)j * 8 * (DIM * 2), lB + j * 1024);
    }
    gA += 128; gB += 128;
    __syncthreads();
#pragma unroll
    for (int c = 0; c < 8; c += 4) {                // logical chunk base (kk = c*8)
      const int po = ((c + jc) ^ cn7) << 3;         // swizzled element offset in row
      bf16x8 aF[4], bF[4];
#pragma unroll
      for (int mi = 0; mi < 4; ++mi)
        aF[mi] = *(const bf16x8*)&lsA[(wm * 64 + mi * 16 + cn) * 64 + po];
#pragma unroll
      for (int ni = 0; ni < 4; ++ni)
        bF[ni] = *(const bf16x8*)&lsB[(wn * 64 + ni * 16 + cn) * 64 + po];
#pragma unroll
      for (int mi = 0; mi < 4; ++mi)
#pragma unroll
        for (int ni = 0; ni < 4; ++ni)
          acc[mi][ni] = __builtin_amdgcn_mfma_f32_16x16x32_bf16(aF[mi], bF[ni], acc[mi][ni], 0, 0, 0);
    }
  }

  // ---- epilogue: per-wave 64x64 transpose through LDS (swizzled), coalesced stores ----
  __syncthreads();                                  // everyone done reading lsA/lsB
  ushort_t* area = ls + wave * 4096;                // 8 KB/wave: 64 rows x 64 cols
  float bv[4];
#pragma unroll
  for (int ni = 0; ni < 4; ++ni) bv[ni] = bvec[s * DIM + eBase + wn * 64 + ni * 16 + cn];
  const int jc4 = jc * 4;
#pragma unroll
  for (int mi = 0; mi < 4; ++mi)
#pragma unroll
    for (int ni = 0; ni < 4; ++ni)
#pragma unroll
      for (int r = 0; r < 4; ++r) {
        const int lr = mi * 16 + jc4 + r;           // local q row
        const int lc = ni * 16 + cn;                // local e col
        const int off = lr * 64 + (((lc >> 3) ^ (lr & 7)) << 3) + (lc & 7);
        area[off] = f2bf(acc[mi][ni][r] + bv[ni]);
      }
  __syncthreads();
  const int rr = lane >> 3;                         // 0..7: row within pass
  const int ch = lane & 7;                          // e-chunk
  const int physc = ch ^ rr;
  const size_t tqs = (size_t)s * (NQ * DIM);
#pragma unroll
  for (int pass = 0; pass < 8; ++pass) {
    const int lr = pass * 8 + rr;
    uint4 v = *(const uint4*)&area[lr * 64 + physc * 8];
    uint32_t wsv[4] = {v.x, v.y, v.z, v.w};
    float ss = 0.f;
#pragma unroll
    for (int i = 0; i < 4; ++i) {
      float lo = bf2f((ushort_t)(wsv[i] & 0xFFFFu));
      float hi = bf2f((ushort_t)(wsv[i] >> 16));
      ss += lo * lo + hi * hi;
    }
    ss += __shfl_xor(ss, 1, 64);
    ss += __shfl_xor(ss, 2, 64);
    ss += __shfl_xor(ss, 4, 64);
    const int q = qBase + wm * 64 + lr;
    *(uint4*)&tq[tqs + (size_t)q * DIM + eBase + wn * 64 + ch * 8] = v;
    if (ch == 0) atomicAdd(&sqq[s * NQ + q], ss);
  }
}

// ================= GEMM2 fused dist/mean/std — 64q x 128p, s-groups {4,4,2} ==============
// Block: 256 threads (4 waves of 32q x 64p), BK=64. Samples grouped {4,4,2}: each staged
// B tile's fragments feed up to 4 samples' MFMAs (0.4 LDS reads/MFMA), barriers 80->48.
// LDS = A 4x8 KB + B 16 KB = 48 KB exactly (proven 2-blocks/CU boundary).
// grid (64,8) q-fastest (proven L3-friendly; avoids R6 cross-XCD co-fetch).
__global__ __launch_bounds__(256, 2) void gemm_dist_kernel(const ushort_t* __restrict__ tq,
                                                           const ushort_t* __restrict__ pb,
                                                           const float* __restrict__ sqq,
                                                           const float* __restrict__ sqp,
                                                           float* __restrict__ out) {
  __shared__ __align__(16) ushort_t lsA[4 * 64 * 64];   // 32 KB: A(s0..s3), row=128B
  __shared__ __align__(16) ushort_t lsB[128 * 64];      // 16 KB
  const int lane = threadIdx.x & 63;
  const int wave = threadIdx.x >> 6;   // 0..3
  const int wm = wave >> 1;            // q offset 32*wm
  const int wn = wave & 1;             // p offset 64*wn
  const int qBase = blockIdx.x * 64;
  const int pBase = blockIdx.y * 128;
  const int srow = lane >> 3;          // 0..7
  const int scol = ((lane & 7) ^ srow) * 16;   // swizzled global chunk (bytes)
  const int cn = lane & 15;
  const int cn7 = cn & 7;
  const int jc = lane >> 4;
  const int rq = jc * 4;
  const floatx4 fzero = {0.f, 0.f, 0.f, 0.f};
  // staging: A 64 rows per sample -> wave covers rows [wave*16,+16) via 2 calls of 8 rows;
  //          B 128 rows -> wave covers rows [wave*32,+32) via 4 calls of 8 rows.
  const char* gAb = (const char*)tq + (size_t)(qBase + wave * 16 + srow) * (DIM * 2) + scol;
  const char* gBb = (const char*)pb + (size_t)(pBase + wave * 32 + srow) * (DIM * 2) + scol;
  char* lAw = (char*)lsA + wave * 2048;          // within each sample's 8 KB quarter
  char* lBw = (char*)lsB + wave * 4096;
  int po[2];
#pragma unroll
  for (int c = 0; c < 2; ++c) po[c] = ((c * 4 + jc) ^ cn7) << 3;

  float sum[2][4][4] = {};   // [mi][ni][r]
  float ssq[2][4][4] = {};
  float sqp_v[4];
#pragma unroll
  for (int ni = 0; ni < 4; ++ni) sqp_v[ni] = sqp[pBase + wn * 64 + ni * 16 + cn];

  for (int grp = 0; grp < 3; ++grp) {
    const int sbase = grp * 4;               // groups: {0..3}, {4..7}, {8..9}
    const int gsz = (grp == 2) ? 2 : 4;
    floatx4 acc[4][2][4];                    // [sp][mi][ni]
#pragma unroll
    for (int sp = 0; sp < 4; ++sp)
#pragma unroll
      for (int mi = 0; mi < 2; ++mi)
#pragma unroll
        for (int ni = 0; ni < 4; ++ni) acc[sp][mi][ni] = fzero;

    const char* gAg = gAb + (size_t)sbase * (NQ * DIM * 2);
    const char* gBk = gBb;
    for (int kt = 0; kt < 8; ++kt) {
      __syncthreads();
#pragma unroll
      for (int sp = 0; sp < 4; ++sp)
        if (sp < gsz) {
          const char* gs = gAg + (size_t)sp * (NQ * DIM * 2);
          char* ls = lAw + sp * 8192;
          gll16(gs, ls);
          gll16(gs + (size_t)8 * (DIM * 2), ls + 1024);
        }
#pragma unroll
      for (int j = 0; j < 4; ++j)
        gll16(gBk + (size_t)j * 8 * (DIM * 2), lBw + j * 1024);
      gAg += 128; gBk += 128;
      __syncthreads();
#pragma unroll
      for (int c = 0; c < 2; ++c) {
        bf16x8 bF[4];
#pragma unroll
        for (int ni = 0; ni < 4; ++ni)
          bF[ni] = *(const bf16x8*)&lsB[(wn * 64 + ni * 16 + cn) * 64 + po[c]];
#pragma unroll
        for (int sp = 0; sp < 4; ++sp)
          if (sp < gsz) {
            bf16x8 aF[2];
#pragma unroll
            for (int mi = 0; mi < 2; ++mi)
              aF[mi] = *(const bf16x8*)&lsA[sp * 4096 + (wm * 32 + mi * 16 + cn) * 64 + po[c]];
#pragma unroll
            for (int mi = 0; mi < 2; ++mi)
#pragma unroll
              for (int ni = 0; ni < 4; ++ni)
                acc[sp][mi][ni] =
                    __builtin_amdgcn_mfma_f32_16x16x32_bf16(aF[mi], bF[ni], acc[sp][mi][ni], 0, 0, 0);
          }
      }
    }
    // fold group samples into running stats (ssq accumulates pre-sqrt sqd)
#pragma unroll
    for (int sp = 0; sp < 4; ++sp)
      if (sp < gsz) {
        const int s = sbase + sp;
#pragma unroll
        for (int mi = 0; mi < 2; ++mi) {
          float4 aqv = *(const float4*)&sqq[s * NQ + qBase + wm * 32 + mi * 16 + rq];
          float aqa[4] = {aqv.x, aqv.y, aqv.z, aqv.w};
#pragma unroll
          for (int r = 0; r < 4; ++r) {
            float aq = aqa[r];
#pragma unroll
            for (int ni = 0; ni < 4; ++ni) {
              float sqd = fmaxf(fmaf(-2.0f, acc[sp][mi][ni][r], aq + sqp_v[ni]), 1e-12f);
              sum[mi][ni][r] += sqrtf(sqd);
              ssq[mi][ni][r] += sqd;
            }
          }
        }
      }
  }
#pragma unroll
  for (int mi = 0; mi < 2; ++mi)
#pragma unroll
    for (int ni = 0; ni < 4; ++ni)
#pragma unroll
      for (int r = 0; r < 4; ++r) {
        int q = qBase + wm * 32 + mi * 16 + rq + r;
        int p = pBase + wn * 64 + ni * 16 + cn;
        float sm = sum[mi][ni][r];
        float mean = sm * 0.1f;
        float var = (ssq[mi][ni][r] - sm * sm * 0.1f) * (1.0f / 9.0f);
        out[(size_t)q * NP + p] = mean;
        out[(size_t)NQ * NP + (size_t)q * NP + p] = sqrtf(fmaxf(var, 0.0f));
      }
}

// ================= launch =================
extern "C" void kernel_launch(void* const* d_in, const int* in_sizes, int n_in,
                              void* d_out, int out_size, void* d_ws, size_t ws_size,
                              hipStream_t stream) {
  const float* qf   = (const float*)d_in[0];
  const float* pf   = (const float*)d_in[1];
  const float* wmu  = (const float*)d_in[2];
  const float* wrho = (const float*)d_in[3];
  const float* bmu  = (const float*)d_in[4];
  const float* brho = (const float*)d_in[5];
  float* out = (float*)d_out;
  char* ws = (char*)d_ws;
  ushort_t* wt   = (ushort_t*)(ws);              //  5,242,880  W^T bf16 [s][e][k]
  ushort_t* qb   = (ushort_t*)(ws + 5242880);    //  4,194,304  query bf16
  ushort_t* pb   = (ushort_t*)(ws + 9437184);    //  1,048,576  proto bf16
  float*    bvec = (float*)   (ws + 10485760);   //     20,480  bias samples
  float*    sqp  = (float*)   (ws + 10506240);   //      4,096  ||p||^2
  ushort_t* tq   = (ushort_t*)(ws + 10510336);   // 41,943,040  tq bf16 [s][q][e]
  float*    sqq  = (float*)   (ws + 52453376);   //    163,840  ||tq||^2 (atomic-accumulated)

  uint32_t kw0, kw1, kb0, kb1;
  threefry2x32(0u, 42u, 0u, 0u, &kw0, &kw1);
  threefry2x32(0u, 42u, 0u, 1u, &kb0, &kb1);

  hipLaunchKernelGGL(prep_kernel, dim3(3124), dim3(256), 0, stream,
                     qf, pf, wmu, wrho, bmu, brho, wt, qb, pb, sqp, bvec, sqq,
                     kw0, kw1, kb0, kb1);
  hipLaunchKernelGGL(gemm_tq_kernel, dim3(32, 4, 10), dim3(256), 0, stream, qb, wt, bvec, tq, sqq);
  hipLaunchKernelGGL(gemm_dist_kernel, dim3(64, 8), dim3(256), 0, stream, tq, pb, sqq, sqp, out);
}